// Round 2
// baseline (393.979 us; speedup 1.0000x reference)
//
#include <hip/hip_runtime.h>
#include <math.h>

// Problem constants (match reference.py)
#define HS_D       1024   // input_size
#define HS_MAXLEN  24     // max Huffman path depth
#define HS_SPW     6      // steps per wave (MAX_LEN / 4 waves)

// One block (256 thr = 4 waves) per example.
// Wave w handles path steps l = w + 4*s, s = 0..5 — ALWAYS all 6 (no branch);
// steps past the true path length L load a valid (random) W row and are
// masked out at the softplus. This lets us issue all 24 float4 W-loads
// back-to-back for memory-level parallelism (latency-bound gather fix).
__global__ __launch_bounds__(256) void hsm_loss_kernel(
    const float* __restrict__ x,      // [N_EX, D]
    const float* __restrict__ W,      // [N_DEC, D]
    const int*   __restrict__ t,      // [N_EX]
    const int*   __restrict__ paths,  // [V, MAX_LEN]
    const float* __restrict__ codes,  // [V, MAX_LEN]
    const int*   __restrict__ lens,   // [V]
    float*       __restrict__ out)    // [1]
{
    const int n    = blockIdx.x;
    const int tid  = threadIdx.x;
    const int wave = tid >> 6;
    const int lane = tid & 63;

    const int leaf = t[n];          // wave-uniform -> scalar load
    const int L    = lens[leaf];    // wave-uniform

    // Wave-uniform path metadata for this wave's 6 steps.
    int   node[HS_SPW];
    float code[HS_SPW];
#pragma unroll
    for (int s = 0; s < HS_SPW; ++s) {
        const int l = wave + 4 * s;          // < 24 always
        node[s] = paths[leaf * HS_MAXLEN + l];
        code[s] = codes[leaf * HS_MAXLEN + l];
    }

    // This lane's fragment of x[n]: 16 floats = 4 x float4, coalesced.
    const float4* x4 = (const float4*)(x + (size_t)n * HS_D);
    float4 xf[4];
#pragma unroll
    for (int j = 0; j < 4; ++j)
        xf[j] = x4[j * 64 + lane];

    // Issue ALL W-row loads (6 steps x 4 float4) before consuming any.
    float4 wf[HS_SPW][4];
#pragma unroll
    for (int s = 0; s < HS_SPW; ++s) {
        const float4* w4 = (const float4*)(W + (size_t)node[s] * HS_D);
#pragma unroll
        for (int j = 0; j < 4; ++j)
            wf[s][j] = w4[j * 64 + lane];
    }

    // 6 independent partial dots per lane.
    float dot[HS_SPW];
#pragma unroll
    for (int s = 0; s < HS_SPW; ++s) {
        float d = 0.0f;
#pragma unroll
        for (int j = 0; j < 4; ++j) {
            d += xf[j].x * wf[s][j].x + xf[j].y * wf[s][j].y
               + xf[j].z * wf[s][j].z + xf[j].w * wf[s][j].w;
        }
        dot[s] = d;
    }

    // Interleaved butterfly reduce: 6 independent shuffle chains (ILP).
#pragma unroll
    for (int off = 32; off > 0; off >>= 1) {
#pragma unroll
        for (int s = 0; s < HS_SPW; ++s)
            dot[s] += __shfl_down(dot[s], off);
    }

    float local = 0.0f;
    if (lane == 0) {
#pragma unroll
        for (int s = 0; s < HS_SPW; ++s) {
            const int l = wave + 4 * s;
            const float z = -code[s] * dot[s];
            // stable softplus(z) = max(z,0) + log1p(exp(-|z|))
            const float sp = fmaxf(z, 0.0f) + log1pf(expf(-fabsf(z)));
            local += (l < L) ? sp : 0.0f;
        }
    }

    __shared__ float sred[4];
    if (lane == 0) sred[wave] = local;
    __syncthreads();
    if (tid == 0) {
        const float blocksum = sred[0] + sred[1] + sred[2] + sred[3];
        atomicAdd(out, blocksum);
    }
}

extern "C" void kernel_launch(void* const* d_in, const int* in_sizes, int n_in,
                              void* d_out, int out_size, void* d_ws, size_t ws_size,
                              hipStream_t stream) {
    const float* x     = (const float*)d_in[0];
    const float* W     = (const float*)d_in[1];
    const int*   t     = (const int*)  d_in[2];
    const int*   paths = (const int*)  d_in[3];
    const float* codes = (const float*)d_in[4];
    const int*   lens  = (const int*)  d_in[5];
    float* out = (float*)d_out;

    const int n_ex = in_sizes[2];  // t has N_EX elements

    // d_out is poisoned with 0xAA before every timed launch -> zero it.
    hipMemsetAsync(out, 0, sizeof(float), stream);

    hsm_loss_kernel<<<n_ex, 256, 0, stream>>>(x, W, t, paths, codes, lens, out);
}

// Round 3
// 324.167 us; speedup vs baseline: 1.2154x; 1.2154x over previous
//
#include <hip/hip_runtime.h>
#include <math.h>

// Problem constants (match reference.py)
#define HS_D       1024   // input_size
#define HS_MAXLEN  24     // max Huffman path depth
#define HS_PAIRS   12     // step-pairs per example (24/2)
#define HS_NBUCKET 512    // partial-sum buckets in d_ws

// One WAVE per (example, step-pair). Each wave:
//   - loads its 16-float fragment of x[n]          (4 x float4, coalesced)
//   - loads 16-float fragments of W[node0],W[node1](8 x float4, coalesced)
//   - two dot products, interleaved butterfly reduce, masked softplus
//   - lane 0 atomicAdd into a staggered bucket in ws
// All loads are useful bytes (invalid trailing step clamps its node to node0,
// whose lines are already in flight -> L1 hit, no HBM waste). Waves whose
// pair is entirely past the path length exit immediately (wave-uniform
// branch), freeing the slot for dispatch of more blocks.
__global__ __launch_bounds__(256) void hsm_pair_kernel(
    const float* __restrict__ x,      // [N_EX, D]
    const float* __restrict__ W,      // [N_DEC, D]
    const int*   __restrict__ t,      // [N_EX]
    const int*   __restrict__ paths,  // [V, MAX_LEN]
    const float* __restrict__ codes,  // [V, MAX_LEN]
    const int*   __restrict__ lens,   // [V]
    float*       __restrict__ ws,     // [HS_NBUCKET] zero-initialized
    int n_ex)
{
    const int tid  = threadIdx.x;
    const int lane = tid & 63;
    const int gw   = blockIdx.x * 4 + (tid >> 6);  // global wave id
    const int n    = gw / HS_PAIRS;                // example
    const int p    = gw % HS_PAIRS;                // step-pair

    const int leaf = t[n];                 // wave-uniform -> scalar load
    const int L    = lens[leaf];           // wave-uniform
    const int l0   = 2 * p;
    const int l1   = l0 + 1;
    if (l0 >= L) return;                   // wave-uniform early exit

    const int   node0 = paths[leaf * HS_MAXLEN + l0];
    const float c0    = codes[leaf * HS_MAXLEN + l0];
    const bool  v1    = (l1 < L);
    // Clamp invalid second step to node0: duplicate address -> L1 hit.
    const int   node1 = v1 ? paths[leaf * HS_MAXLEN + l1] : node0;
    const float c1    = v1 ? codes[leaf * HS_MAXLEN + l1] : 1.0f;

    const float4* x4 = (const float4*)(x + (size_t)n     * HS_D);
    const float4* w0 = (const float4*)(W + (size_t)node0 * HS_D);
    const float4* w1 = (const float4*)(W + (size_t)node1 * HS_D);

    // Issue all 12 loads before consuming (12 float4 = 48 VGPRs: fits).
    float4 xf[4], wf0[4], wf1[4];
#pragma unroll
    for (int j = 0; j < 4; ++j) xf[j]  = x4[j * 64 + lane];
#pragma unroll
    for (int j = 0; j < 4; ++j) wf0[j] = w0[j * 64 + lane];
#pragma unroll
    for (int j = 0; j < 4; ++j) wf1[j] = w1[j * 64 + lane];

    float d0 = 0.0f, d1 = 0.0f;
#pragma unroll
    for (int j = 0; j < 4; ++j) {
        d0 += xf[j].x * wf0[j].x + xf[j].y * wf0[j].y
            + xf[j].z * wf0[j].z + xf[j].w * wf0[j].w;
        d1 += xf[j].x * wf1[j].x + xf[j].y * wf1[j].y
            + xf[j].z * wf1[j].z + xf[j].w * wf1[j].w;
    }

    // Two interleaved 64-lane butterfly reductions.
#pragma unroll
    for (int off = 32; off > 0; off >>= 1) {
        d0 += __shfl_down(d0, off);
        d1 += __shfl_down(d1, off);
    }

    if (lane == 0) {
        const float z0 = -c0 * d0;
        float v = fmaxf(z0, 0.0f) + log1pf(expf(-fabsf(z0)));
        if (v1) {
            const float z1 = -c1 * d1;
            v += fmaxf(z1, 0.0f) + log1pf(expf(-fabsf(z1)));
        }
        atomicAdd(&ws[gw & (HS_NBUCKET - 1)], v);
    }
}

// Single-wave finish: sum the buckets, write the scalar output.
__global__ __launch_bounds__(64) void hsm_finish_kernel(
    const float* __restrict__ ws, float* __restrict__ out)
{
    const int lane = threadIdx.x;
    float s = 0.0f;
#pragma unroll
    for (int k = 0; k < HS_NBUCKET / 64; ++k)
        s += ws[lane + 64 * k];
#pragma unroll
    for (int off = 32; off > 0; off >>= 1)
        s += __shfl_down(s, off);
    if (lane == 0) out[0] = s;
}

extern "C" void kernel_launch(void* const* d_in, const int* in_sizes, int n_in,
                              void* d_out, int out_size, void* d_ws, size_t ws_size,
                              hipStream_t stream) {
    const float* x     = (const float*)d_in[0];
    const float* W     = (const float*)d_in[1];
    const int*   t     = (const int*)  d_in[2];
    const int*   paths = (const int*)  d_in[3];
    const float* codes = (const float*)d_in[4];
    const int*   lens  = (const int*)  d_in[5];
    float* out = (float*)d_out;
    float* ws  = (float*)d_ws;

    const int n_ex = in_sizes[2];  // t has N_EX elements

    // ws is re-poisoned 0xAA before every timed launch -> zero the buckets.
    hipMemsetAsync(ws, 0, HS_NBUCKET * sizeof(float), stream);

    const int n_waves  = n_ex * HS_PAIRS;
    const int n_blocks = (n_waves + 3) / 4;   // 4 waves per 256-thr block
    hsm_pair_kernel<<<n_blocks, 256, 0, stream>>>(x, W, t, paths, codes, lens,
                                                  ws, n_ex);
    hsm_finish_kernel<<<1, 64, 0, stream>>>(ws, out);
}